// Round 9
// baseline (479.043 us; speedup 1.0000x reference)
//
#include <hip/hip_runtime.h>
#include <cstdint>
#include <cstddef>

#define E_EDGES 800000
#define N_NODES 50000
#define HDIM 128
#define HID 256
#define ME 64            // edges per block in edge kernel
#define NB 64            // nodes per block in node/hab kernels
#define NTILES 196       // ceil(N_NODES/256) for the parallel scan

typedef __attribute__((ext_vector_type(8))) short short8;
typedef __attribute__((ext_vector_type(4))) float f32x4;
typedef __attribute__((ext_vector_type(4))) unsigned int u32x4;

// fast silu: y * rcp(1 + exp(-y)); v_rcp_f32 ~1ulp, fine vs bf16 rounding
__device__ __forceinline__ float silu(float y) {
    return y * __builtin_amdgcn_rcpf(1.0f + __expf(-y));
}

// native RNE f32 -> bf16
__device__ __forceinline__ short f2bfn(float f) {
    __bf16 b = (__bf16)f;
    return __builtin_bit_cast(short, b);
}
__device__ __forceinline__ float bf2f(short s) {
    return __uint_as_float(((unsigned int)(unsigned short)s) << 16);
}

// forced-batch 16B global load: volatile asm cannot be sunk/serialized by the
// scheduler (r19-r21: compiler refuses to keep >1 gather load in flight at any
// register budget). Consumers depend on WAIT8's "+v" outputs -> no use can be
// scheduled before the waitcnt (SSA dep, not memory dep).
#define GLD(dst, addr, imm) \
    asm volatile("global_load_dwordx4 %0, %1, off offset:" imm \
                 : "=v"(dst) : "v"(addr))
#define WAIT8(x0, x1, x2, x3, x4, x5, x6, x7) \
    asm volatile("s_waitcnt vmcnt(0)" \
                 : "+v"(x0), "+v"(x1), "+v"(x2), "+v"(x3), \
                   "+v"(x4), "+v"(x5), "+v"(x6), "+v"(x7) :: "memory")

// ---------------- fused prep: h cvt + agg zero + hist + all weight cvts ----------------
// (cnt must be zeroed BEFORE this kernel: hist atomicAdds into it here)
// Wab  [512][160]: c<256: k<128 = We1[c][k],        k=128 = be1[c], else 0   (A-half)
//                  c>=256: k<128 = We1[c-256][128+k], else 0                 (B-half)
// wrf  [256] f32 : We1[c][256]  (radial column, exact f32)
// Wb2  [256][288]: k<256 = We2, k=256 = be2, else 0
// Wbn1 [256][416]: k<384 = Wn1, k=384 = bn1, else 0
// Wbn2 [128][288]: k<256 = Wn2, k=256 = bn2, else 0
#define PREP_H    6250                    // h fp32->bf16, 1600000 short4
#define PREP_AGG  (PREP_H + 12500)        // agg zero, 3200000 float4
#define PREP_HIST (PREP_AGG + 3125)       // hist over 800000 edges
#define PREP_WAB  (PREP_HIST + 320)       // 512*160
#define PREP_WRF  (PREP_WAB + 1)          // 256 f32
#define PREP_WE2  (PREP_WRF + 288)
#define PREP_WN1  (PREP_WE2 + 416)
#define PREP_WN2  (PREP_WN1 + 144)
__global__ void prep_kernel(const float* __restrict__ h, short* __restrict__ hbf,
                            float* __restrict__ agg,
                            const int* __restrict__ row, int* __restrict__ cnt,
                            const float* __restrict__ We1, const float* __restrict__ be1,
                            short* __restrict__ Wab, float* __restrict__ wrf,
                            const float* __restrict__ We2, const float* __restrict__ be2,
                            short* __restrict__ Wb2,
                            const float* __restrict__ Wn1, const float* __restrict__ bn1,
                            short* __restrict__ Wbn1,
                            const float* __restrict__ Wn2, const float* __restrict__ bn2,
                            short* __restrict__ Wbn2) {
    const int b = blockIdx.x, t = threadIdx.x;
    if (b < PREP_H) {
        int i = b * 256 + t;                      // quad index
        float4 v = ((const float4*)h)[i];
        short4 s;
        s.x = f2bfn(v.x); s.y = f2bfn(v.y); s.z = f2bfn(v.z); s.w = f2bfn(v.w);
        ((short4*)hbf)[i] = s;
    } else if (b < PREP_AGG) {
        int i = (b - PREP_H) * 256 + t;           // float4 index
        ((float4*)agg)[i] = make_float4(0.f, 0.f, 0.f, 0.f);
    } else if (b < PREP_HIST) {
        int e = (b - PREP_AGG) * 256 + t;
        if (e < E_EDGES) atomicAdd(&cnt[row[e]], 1);
    } else if (b < PREP_WAB) {
        int idx = (b - PREP_HIST) * 256 + t;      // 512*160
        int c = idx / 160, k = idx - c * 160;
        short v = 0;
        if (c < 256) {
            if (k < 128)       v = f2bfn(We1[c * 257 + k]);
            else if (k == 128) v = f2bfn(be1[c]);
        } else {
            if (k < 128)       v = f2bfn(We1[(c - 256) * 257 + 128 + k]);
        }
        Wab[idx] = v;
    } else if (b < PREP_WRF) {
        wrf[t] = We1[t * 257 + 256];
    } else if (b < PREP_WE2) {
        int idx = (b - PREP_WRF) * 256 + t;       // 256*288
        int c = idx / 288, k = idx - c * 288;
        short v = 0;
        if (k < 256)       v = f2bfn(We2[c * 256 + k]);
        else if (k == 256) v = f2bfn(be2[c]);
        Wb2[idx] = v;
    } else if (b < PREP_WN1) {
        int idx = (b - PREP_WE2) * 256 + t;       // 256*416
        int c = idx / 416, k = idx - c * 416;
        short v = 0;
        if (k < 384)       v = f2bfn(Wn1[c * 384 + k]);
        else if (k == 384) v = f2bfn(bn1[c]);
        Wbn1[idx] = v;
    } else {
        int idx = (b - PREP_WN1) * 256 + t;       // 128*288
        int c = idx / 288, k = idx - c * 288;
        short v = 0;
        if (k < 256)       v = f2bfn(Wn2[c * 256 + k]);
        else if (k == 256) v = f2bfn(bn2[c]);
        Wbn2[idx] = v;
    }
}

// ---------------- parallel CSR scan (3 small kernels) ----------------
__global__ void scanA_kernel(const int* __restrict__ cnt, int* __restrict__ incl,
                             int* __restrict__ tsum) {
    const int b = blockIdx.x, t = threadIdx.x;
    const int i = b * 256 + t;
    const int lane = t & 63, wv = t >> 6;
    int v = (i < N_NODES) ? cnt[i] : 0;
    int s = v;
#pragma unroll
    for (int off = 1; off < 64; off <<= 1) {
        int u = __shfl_up(s, off, 64);
        if (lane >= off) s += u;
    }
    __shared__ int wsum[4];
    if (lane == 63) wsum[wv] = s;
    __syncthreads();
    int pre = 0;
#pragma unroll
    for (int j = 0; j < 3; ++j) if (wv > j) pre += wsum[j];
    s += pre;
    if (i < N_NODES) incl[i] = s;
    if (t == 255) tsum[b] = s;
}

__global__ void scanB_kernel(const int* __restrict__ tsum, int* __restrict__ toff) {
    const int t = threadIdx.x;
    const int lane = t & 63, wv = t >> 6;
    int v = (t < NTILES) ? tsum[t] : 0;
    int s = v;
#pragma unroll
    for (int off = 1; off < 64; off <<= 1) {
        int u = __shfl_up(s, off, 64);
        if (lane >= off) s += u;
    }
    __shared__ int wsum[4];
    if (lane == 63) wsum[wv] = s;
    __syncthreads();
    int pre = 0;
#pragma unroll
    for (int j = 0; j < 3; ++j) if (wv > j) pre += wsum[j];
    s += pre;
    if (t < NTILES) toff[t] = s - v;   // exclusive
}

__global__ void scanC_kernel(const int* __restrict__ cnt, int* __restrict__ cursor,
                             const int* __restrict__ toff) {
    const int b = blockIdx.x, t = threadIdx.x;
    const int i = b * 256 + t;
    if (i < N_NODES) {
        cursor[i] = cursor[i] - cnt[i] + toff[b];   // incl -> excl + tile offset
    }
}

__global__ void fill_kernel(const int* __restrict__ row, int* __restrict__ cursor,
                            int* __restrict__ eidx) {
    int e = blockIdx.x * 256 + threadIdx.x;
    if (e < E_EDGES) {
        int pos = atomicAdd(&cursor[row[e]], 1);
        eidx[pos] = e;
    }
}

// ---------------- hab precompute: hab[n] = [h.Wa^T + be1 | h.Wb^T] (bf16) ----------------
// r24-proven: swapped-MFMA epilogue (lane holds 4 consecutive channels) ->
// packed short4 LDS stores -> coalesced short8 copy-out (8 chunks/thread).
__global__ __launch_bounds__(256, 4) void hab_kernel(
    const short* __restrict__ hbf, const short* __restrict__ Wab,
    short* __restrict__ hab)
{
    __shared__ __align__(16) short pool[NB * 256];  // 32 KB: shH (16KB) in GEMM; shO overlays
    __shared__ __align__(16) short shTh[NB * 32];   // 4 KB bias K-tail {1,0,..}
    short* shH = pool;                  // [64][128] bf16 (swizzled) during GEMM
    short* shO = pool;                  // [64][256] bf16 (swizzled) after barrier

    const int t = threadIdx.x;
    const int tile = blockIdx.x >> 1;
    const int half = blockIdx.x & 1;
    const int n0 = tile * NB;

    {
        const int n = t >> 2, q = t & 3;
        int gn = n0 + n;
        if (gn >= N_NODES) gn = N_NODES - 1;   // clamp loads; stores guarded
        const short8* hp = (const short8*)(hbf + (size_t)gn * HDIM + q * 32);
#pragma unroll
        for (int c = 0; c < 4; ++c) {
            short8 v = hp[c];
            int chunk = q * 4 + c;             // 0..15
            *(short8*)&shH[n * 128 + ((chunk ^ (n & 7)) << 3)] = v;
        }
        short8 z = {0, 0, 0, 0, 0, 0, 0, 0};
        if (q == 0) z[0] = (short)0x3F80;      // bf16 1.0
        *(short8*)&shTh[n * 32 + ((q ^ (n & 3)) << 3)] = z;
    }
    __syncthreads();

    const int l = t & 63, w = t >> 6;
    const int l15 = l & 15, lq = l >> 4;

    f32x4 acc[4][4];                    // SWAPPED: acc[ct][et], rows=channels
#pragma unroll
    for (int i = 0; i < 4; ++i)
#pragma unroll
        for (int j = 0; j < 4; ++j) acc[i][j] = (f32x4){0.f, 0.f, 0.f, 0.f};

#pragma unroll
    for (int ks = 0; ks < 5; ++ks) {
        short8 a[4], b[4];
#pragma unroll
        for (int et = 0; et < 4; ++et) {
            int r = et * 16 + l15;
            if (ks < 4) {
                int chunk = ks * 4 + lq;
                a[et] = *(const short8*)&shH[r * 128 + ((chunk ^ (r & 7)) << 3)];
            } else {
                a[et] = *(const short8*)&shTh[r * 32 + ((lq ^ (r & 3)) << 3)];
            }
        }
#pragma unroll
        for (int ct = 0; ct < 4; ++ct) {
            int cc = half * 256 + w * 64 + ct * 16 + l15;
            b[ct] = *(const short8*)&Wab[cc * 160 + ks * 32 + lq * 8];
        }
#pragma unroll
        for (int et = 0; et < 4; ++et)
#pragma unroll
            for (int ct = 0; ct < 4; ++ct)
                acc[ct][et] = __builtin_amdgcn_mfma_f32_16x16x32_bf16(
                    b[ct], a[et], acc[ct][et], 0, 0, 0);
    }
    __syncthreads();   // done reading shH before shO overlay

    // ---- swapped epilogue: packed short4 LDS stores (bank floor) ----
    {
#pragma unroll
        for (int ct = 0; ct < 4; ++ct) {
#pragma unroll
            for (int et = 0; et < 4; ++et) {
                int n = et * 16 + l15;                 // node (acc col)
                int chb = w * 64 + ct * 16 + lq * 4;   // within-half channel base
                short4 s;
                s.x = f2bfn(acc[ct][et][0]);
                s.y = f2bfn(acc[ct][et][1]);
                s.z = f2bfn(acc[ct][et][2]);
                s.w = f2bfn(acc[ct][et][3]);
                int chunk = chb >> 3;                  // chb % 4 == 0: stays in one chunk
                *(short4*)&shO[n * 256 + ((chunk ^ (n & 7)) << 3) + (chb & 7)] = s;
            }
        }
    }
    __syncthreads();

    // ---- coalesced copy-out: 4 threads/node, 8x short8 (16B) each = 256 ch ----
    {
        const int n = t >> 2, q = t & 3;
        int gn = n0 + n;
        if (gn < N_NODES) {
            short* dst = hab + (size_t)gn * 512 + half * 256;
#pragma unroll
            for (int c = 0; c < 8; ++c) {
                int chunk = c * 4 + q;                 // 0..31
                short8 v = *(const short8*)&shO[n * 256 + ((chunk ^ (n & 7)) << 3)];
                *(short8*)&dst[chunk * 8] = v;
            }
        }
    }
}

// ---------------- edge MLP (forced-batch gather + fused layer-1) + segmented scatter -----
// r25: staging gather via inline-asm global_load_dwordx4 in 2 rounds of 8 with
// a single counted s_waitcnt per round. The compiler demonstrably refuses to
// keep >1 gather load in flight (r19: VGPR=64@4w, r21: VGPR=68@3w, r22: DMA) --
// volatile asm forces 8 outstanding. 2 rounds keep peak batch regs at 32 so
// the 64-AGPR acc + staging fit (256,4)'s 128-reg budget: occupancy stays
// 4 blocks/CU (the property every slower variant lost).
__global__ __launch_bounds__(256, 4) void edge_kernel(
    const short* __restrict__ hab, const float* __restrict__ coord,
    const int* __restrict__ row, const int* __restrict__ col,
    const int* __restrict__ eidx, const float* __restrict__ wrf,
    const short* __restrict__ Wb2, float* __restrict__ agg)
{
    __shared__ __align__(16) short shPool[ME * 256 + ME * 32];
    __shared__ int sr[ME];
    short* shA = shPool;
    short* shT = shPool + ME * 256;

    const int t = threadIdx.x;
    const int nwg = E_EDGES / ME;
    const int qq = nwg >> 3, rr = nwg & 7;
    const int xcd = blockIdx.x & 7, bi = blockIdx.x >> 3;
    const int wg = (xcd < rr ? xcd * (qq + 1) : rr * (qq + 1) + (xcd - rr) * qq) + bi;
    const int e0 = wg * ME;

    // ---- stage: forced-batch gather of A/B rows, fuse radial + silu -> M1 ----
    {
        const int e = t >> 2, q = t & 3;       // 4 threads/edge, 64 ch each
        const int eo = eidx[e0 + e];
        const int rsrc = row[eo];
        const int csrc = col[eo];
        float cx = coord[3 * eo + 0];
        float cy = coord[3 * eo + 1];
        float cz = coord[3 * eo + 2];
        float radial = cx * cx + cy * cy + cz * cz;
        const short* ApS = hab + (size_t)rsrc * 512 + q * 64;
        const short* BpS = hab + (size_t)csrc * 512 + 256 + q * 64;
        const f32x4* Wp = (const f32x4*)(wrf + q * 64);

        u32x4 va[4], vb[4];
        // ---- round 1: chunks q*8 + (0..3), byte offsets 0..48 ----
        GLD(va[0], ApS, "0");  GLD(va[1], ApS, "16");
        GLD(va[2], ApS, "32"); GLD(va[3], ApS, "48");
        GLD(vb[0], BpS, "0");  GLD(vb[1], BpS, "16");
        GLD(vb[2], BpS, "32"); GLD(vb[3], BpS, "48");
        WAIT8(va[0], va[1], va[2], va[3], vb[0], vb[1], vb[2], vb[3]);
#pragma unroll
        for (int j = 0; j < 4; ++j) {
            short8 a = __builtin_bit_cast(short8, va[j]);
            short8 b = __builtin_bit_cast(short8, vb[j]);
            f32x4 w0 = Wp[2 * j], w1 = Wp[2 * j + 1];
            short8 o;
#pragma unroll
            for (int u = 0; u < 4; ++u)
                o[u] = f2bfn(silu(bf2f(a[u]) + bf2f(b[u]) + radial * w0[u]));
#pragma unroll
            for (int u = 0; u < 4; ++u)
                o[4 + u] = f2bfn(silu(bf2f(a[4 + u]) + bf2f(b[4 + u]) + radial * w1[u]));
            int chunk = q * 8 + j;
            *(short8*)&shA[e * 256 + ((chunk ^ (e & 7)) << 3)] = o;
        }
        // ---- round 2: chunks q*8 + (4..7), byte offsets 64..112 ----
        GLD(va[0], ApS, "64"); GLD(va[1], ApS, "80");
        GLD(va[2], ApS, "96"); GLD(va[3], ApS, "112");
        GLD(vb[0], BpS, "64"); GLD(vb[1], BpS, "80");
        GLD(vb[2], BpS, "96"); GLD(vb[3], BpS, "112");
        WAIT8(va[0], va[1], va[2], va[3], vb[0], vb[1], vb[2], vb[3]);
#pragma unroll
        for (int j = 0; j < 4; ++j) {
            short8 a = __builtin_bit_cast(short8, va[j]);
            short8 b = __builtin_bit_cast(short8, vb[j]);
            f32x4 w0 = Wp[2 * (j + 4)], w1 = Wp[2 * (j + 4) + 1];
            short8 o;
#pragma unroll
            for (int u = 0; u < 4; ++u)
                o[u] = f2bfn(silu(bf2f(a[u]) + bf2f(b[u]) + radial * w0[u]));
#pragma unroll
            for (int u = 0; u < 4; ++u)
                o[4 + u] = f2bfn(silu(bf2f(a[4 + u]) + bf2f(b[4 + u]) + radial * w1[u]));
            int chunk = q * 8 + j + 4;
            *(short8*)&shA[e * 256 + ((chunk ^ (e & 7)) << 3)] = o;
        }
        short8 z = {0, 0, 0, 0, 0, 0, 0, 0};
        if (q == 0) {
            z[0] = (short)0x3F80;              // bf16 1.0 (bias multiplier)
            sr[e] = rsrc;
        }
        *(short8*)&shT[e * 32 + ((q ^ (e & 3)) << 3)] = z;
    }
    __syncthreads();

    const int l = t & 63, w = t >> 6;
    const int l15 = l & 15, lq = l >> 4;

    // ---- layer 2: K=256 (+32 tail: bias) MFMA ----
    f32x4 acc[4][4];
#pragma unroll
    for (int i = 0; i < 4; ++i)
#pragma unroll
        for (int j = 0; j < 4; ++j) acc[i][j] = (f32x4){0.f, 0.f, 0.f, 0.f};
#pragma unroll
    for (int ks = 0; ks < 8; ++ks) {
        short8 a[4], b[4];
#pragma unroll
        for (int et = 0; et < 4; ++et) {
            int r = et * 16 + l15;
            int chunk = ks * 4 + lq;
            a[et] = *(const short8*)&shA[r * 256 + ((chunk ^ (r & 7)) << 3)];
        }
#pragma unroll
        for (int ct = 0; ct < 4; ++ct) {
            int cc = w * 64 + ct * 16 + l15;
            b[ct] = *(const short8*)&Wb2[cc * 288 + ks * 32 + lq * 8];
        }
        __builtin_amdgcn_s_setprio(1);
#pragma unroll
        for (int et = 0; et < 4; ++et)
#pragma unroll
            for (int ct = 0; ct < 4; ++ct)
                acc[et][ct] = __builtin_amdgcn_mfma_f32_16x16x32_bf16(
                    a[et], b[ct], acc[et][ct], 0, 0, 0);
        __builtin_amdgcn_s_setprio(0);
    }
    {   // tail K-step: bias (A = {1.0,0...})
        short8 a[4], b[4];
#pragma unroll
        for (int et = 0; et < 4; ++et) {
            int r = et * 16 + l15;
            a[et] = *(const short8*)&shT[r * 32 + ((lq ^ (r & 3)) << 3)];
        }
#pragma unroll
        for (int ct = 0; ct < 4; ++ct) {
            int cc = w * 64 + ct * 16 + l15;
            b[ct] = *(const short8*)&Wb2[cc * 288 + 256 + lq * 8];
        }
        __builtin_amdgcn_s_setprio(1);
#pragma unroll
        for (int et = 0; et < 4; ++et)
#pragma unroll
            for (int ct = 0; ct < 4; ++ct)
                acc[et][ct] = __builtin_amdgcn_mfma_f32_16x16x32_bf16(
                    a[et], b[ct], acc[et][ct], 0, 0, 0);
        __builtin_amdgcn_s_setprio(0);
    }
    __syncthreads();

    // ---- SiLU -> C2 TRANSPOSED [n][e], stride 68, packed short4 writes ----
    {
#pragma unroll
        for (int ct = 0; ct < 4; ++ct) {
#pragma unroll
            for (int et = 0; et < 4; ++et) {
                int kc = w * 64 + ct * 16 + l15;
                int er0 = et * 16 + lq * 4;
                short4 s;
                s.x = f2bfn(silu(acc[et][ct][0]));
                s.y = f2bfn(silu(acc[et][ct][1]));
                s.z = f2bfn(silu(acc[et][ct][2]));
                s.w = f2bfn(silu(acc[et][ct][3]));
                *(short4*)&shPool[kc * 68 + er0] = s;
            }
        }
    }
    __syncthreads();

    // ---- segmented reduction (vectorized short4 reads); coalesced atomics ----
    // segment ids are wave-uniform -> readfirstlane pins the compare/branch to SALU
    {
        const int cc = t;
        const short* myrow = &shPool[cc * 68];
        float accum = 0.f;
        int cur = __builtin_amdgcn_readfirstlane(sr[0]);
        for (int eb = 0; eb < ME; eb += 4) {
            short4 v4 = *(const short4*)&myrow[eb];
            short vj[4] = {v4.x, v4.y, v4.z, v4.w};
#pragma unroll
            for (int j = 0; j < 4; ++j) {
                float v = bf2f(vj[j]);
                int r = __builtin_amdgcn_readfirstlane(sr[eb + j]);
                if (r != cur) {
                    atomicAdd(&agg[(size_t)cur * HID + cc], accum);
                    accum = v;
                    cur = r;
                } else {
                    accum += v;
                }
            }
        }
        atomicAdd(&agg[(size_t)cur * HID + cc], accum);
    }
}

// ---------------- node MLP (bf16 MFMA), 64 nodes/block, biases via MFMA tails ----------------
__global__ __launch_bounds__(256, 3) void node_kernel(
    const short* __restrict__ hbf, const float* __restrict__ agg,
    const short* __restrict__ Wbn1, const short* __restrict__ Wbn2,
    float* __restrict__ out)
{
    __shared__ __align__(16) short pool[NB * 384];  // 48 KB: shH + shAg; shM overlays
    __shared__ __align__(16) short shTn[NB * 32];   // 4 KB bias K-tail {1,0,..}
    short* shH  = pool;                 // [64][128] bf16 (swizzled)
    short* shAg = pool + NB * 128;      // [64][256] bf16 (swizzled)
    short* shM  = pool;                 // [64][256] bf16 (swizzled) — overlays

    const int t  = threadIdx.x;
    const int n0 = blockIdx.x * NB;

    // ---- stage h (bf16 copy), agg (f32 -> bf16), bias tail; 4 threads/node ----
    {
        const int n = t >> 2, q = t & 3;
        int gn = n0 + n;
        if (gn >= N_NODES) gn = N_NODES - 1;   // clamp loads; stores guarded later
        const short8* hp = (const short8*)(hbf + (size_t)gn * HDIM + q * 32);
#pragma unroll
        for (int c = 0; c < 4; ++c) {
            short8 v = hp[c];
            int chunk = q * 4 + c;             // 0..15
            int sw = chunk ^ (n & 7);
            *(short8*)&shH[n * 128 + sw * 8] = v;
        }
        const float4* ap = (const float4*)(agg + (size_t)gn * HID + q * 64);
#pragma unroll
        for (int i = 0; i < 8; ++i) {
            float4 u0 = ap[2 * i], u1 = ap[2 * i + 1];
            short8 s;
            s[0] = f2bfn(u0.x); s[1] = f2bfn(u0.y); s[2] = f2bfn(u0.z); s[3] = f2bfn(u0.w);
            s[4] = f2bfn(u1.x); s[5] = f2bfn(u1.y); s[6] = f2bfn(u1.z); s[7] = f2bfn(u1.w);
            int chunk = q * 8 + i;             // 0..31
            int sw2 = chunk ^ (n & 7);
            *(short8*)&shAg[n * 256 + sw2 * 8] = s;
        }
        short8 z = {0, 0, 0, 0, 0, 0, 0, 0};
        if (q == 0) z[0] = (short)0x3F80;      // bf16 1.0
        *(short8*)&shTn[n * 32 + ((q ^ (n & 3)) << 3)] = z;
    }
    __syncthreads();

    const int l = t & 63, w = t >> 6;
    const int l15 = l & 15, lq = l >> 4;

    // ---- layer 1: K=384 (+32 bias tail), 256 cols, 64 rows ----
    f32x4 acc[4][4];
#pragma unroll
    for (int i = 0; i < 4; ++i)
#pragma unroll
        for (int j = 0; j < 4; ++j) acc[i][j] = (f32x4){0.f, 0.f, 0.f, 0.f};
#pragma unroll
    for (int ks = 0; ks < 12; ++ks) {
        short8 a[4], b[4];
#pragma unroll
        for (int et = 0; et < 4; ++et) {
            int r = et * 16 + l15;
            if (ks < 4) {
                int chunk = ks * 4 + lq;
                a[et] = *(const short8*)&shH[r * 128 + ((chunk ^ (r & 7)) << 3)];
            } else {
                int chunk = (ks - 4) * 4 + lq;
                a[et] = *(const short8*)&shAg[r * 256 + ((chunk ^ (r & 7)) << 3)];
            }
        }
#pragma unroll
        for (int ct = 0; ct < 4; ++ct) {
            int cc = w * 64 + ct * 16 + l15;
            b[ct] = *(const short8*)&Wbn1[cc * 416 + ks * 32 + lq * 8];
        }
#pragma unroll
        for (int et = 0; et < 4; ++et)
#pragma unroll
            for (int ct = 0; ct < 4; ++ct)
                acc[et][ct] = __builtin_amdgcn_mfma_f32_16x16x32_bf16(
                    a[et], b[ct], acc[et][ct], 0, 0, 0);
    }
    {   // bias tail (k = 384..415)
        short8 a[4], b[4];
#pragma unroll
        for (int et = 0; et < 4; ++et) {
            int r = et * 16 + l15;
            a[et] = *(const short8*)&shTn[r * 32 + ((lq ^ (r & 3)) << 3)];
        }
#pragma unroll
        for (int ct = 0; ct < 4; ++ct) {
            int cc = w * 64 + ct * 16 + l15;
            b[ct] = *(const short8*)&Wbn1[cc * 416 + 384 + lq * 8];
        }
#pragma unroll
        for (int et = 0; et < 4; ++et)
#pragma unroll
            for (int ct = 0; ct < 4; ++ct)
                acc[et][ct] = __builtin_amdgcn_mfma_f32_16x16x32_bf16(
                    a[et], b[ct], acc[et][ct], 0, 0, 0);
    }
    __syncthreads();   // done reading shH/shAg before shM overlay write

    // ---- SiLU -> M (bf16, swizzled; no bias add) ----
    {
#pragma unroll
        for (int et = 0; et < 4; ++et) {
#pragma unroll
            for (int rp = 0; rp < 2; ++rp) {
                int er0 = et * 16 + lq * 4 + rp * 2;
#pragma unroll
                for (int ct = 0; ct < 4; ++ct) {
                    int kc = w * 64 + ct * 16 + l15;
                    float y0 = silu(acc[et][ct][rp * 2]);
                    float y1 = silu(acc[et][ct][rp * 2 + 1]);
                    int khi = kc >> 3, klo = kc & 7;
                    shM[er0 * 256 + ((khi ^ (er0 & 7)) << 3) + klo] = f2bfn(y0);
                    shM[(er0 + 1) * 256 + ((khi ^ ((er0 + 1) & 7)) << 3) + klo] = f2bfn(y1);
                }
            }
        }
    }
    __syncthreads();

    // ---- layer 2: K=256 (+32 bias tail), 128 cols (32 per wave), 64 rows ----
    f32x4 acc2[4][2];
#pragma unroll
    for (int i = 0; i < 4; ++i)
#pragma unroll
        for (int j = 0; j < 2; ++j) acc2[i][j] = (f32x4){0.f, 0.f, 0.f, 0.f};
#pragma unroll
    for (int ks = 0; ks < 8; ++ks) {
        short8 a[4], b2[2];
#pragma unroll
        for (int et = 0; et < 4; ++et) {
            int r = et * 16 + l15;
            int chunk = ks * 4 + lq;
            a[et] = *(const short8*)&shM[r * 256 + ((chunk ^ (r & 7)) << 3)];
        }
#pragma unroll
        for (int ct = 0; ct < 2; ++ct) {
            int cc = w * 32 + ct * 16 + l15;
            b2[ct] = *(const short8*)&Wbn2[cc * 288 + ks * 32 + lq * 8];
        }
#pragma unroll
        for (int et = 0; et < 4; ++et)
#pragma unroll
            for (int ct = 0; ct < 2; ++ct)
                acc2[et][ct] = __builtin_amdgcn_mfma_f32_16x16x32_bf16(
                    a[et], b2[ct], acc2[et][ct], 0, 0, 0);
    }
    {   // bias tail (k = 256..287); shTn not overlaid
        short8 a[4], b2[2];
#pragma unroll
        for (int et = 0; et < 4; ++et) {
            int r = et * 16 + l15;
            a[et] = *(const short8*)&shTn[r * 32 + ((lq ^ (r & 3)) << 3)];
        }
#pragma unroll
        for (int ct = 0; ct < 2; ++ct) {
            int cc = w * 32 + ct * 16 + l15;
            b2[ct] = *(const short8*)&Wbn2[cc * 288 + 256 + lq * 8];
        }
#pragma unroll
        for (int et = 0; et < 4; ++et)
#pragma unroll
            for (int ct = 0; ct < 2; ++ct)
                acc2[et][ct] = __builtin_amdgcn_mfma_f32_16x16x32_bf16(
                    a[et], b2[ct], acc2[et][ct], 0, 0, 0);
    }

    // ---- store (bias already in acc2) ----
#pragma unroll
    for (int et = 0; et < 4; ++et) {
#pragma unroll
        for (int ct = 0; ct < 2; ++ct) {
            int cc = w * 32 + ct * 16 + l15;
#pragma unroll
            for (int r4 = 0; r4 < 4; ++r4) {
                int gn = n0 + et * 16 + lq * 4 + r4;
                if (gn < N_NODES)
                    out[(size_t)gn * HDIM + cc] = acc2[et][ct][r4];
            }
        }
    }
}

extern "C" void kernel_launch(void* const* d_in, const int* in_sizes, int n_in,
                              void* d_out, int out_size, void* d_ws, size_t ws_size,
                              hipStream_t stream) {
    const float* h   = (const float*)d_in[0];
    const float* cd  = (const float*)d_in[1];
    const int*   row = (const int*)d_in[2];
    const int*   col = (const int*)d_in[3];
    const float* We1 = (const float*)d_in[4];
    const float* be1 = (const float*)d_in[5];
    const float* We2 = (const float*)d_in[6];
    const float* be2 = (const float*)d_in[7];
    const float* Wn1 = (const float*)d_in[8];
    const float* bn1 = (const float*)d_in[9];
    const float* Wn2 = (const float*)d_in[10];
    const float* bn2 = (const float*)d_in[11];
    float* out = (float*)d_out;

    // ---- workspace layout ----
    short* Wab  = (short*)d_ws;                       // 512*160
    short* Wb2  = Wab + 512 * 160;                    // 256*288
    short* Wbn1 = Wb2 + 256 * 288;                    // 256*416
    short* Wbn2 = Wbn1 + 256 * 416;                   // 128*288
    float* wrf  = (float*)(Wbn2 + 128 * 288);         // 256 f32
    short* hbf  = (short*)(wrf + 256);                // 50000*128
    short* hab  = hbf + (size_t)N_NODES * HDIM;       // 50000*512 bf16
    float* agg  = (float*)(hab + (size_t)N_NODES * 512);   // 50000*256 f32
    int*   cnt    = (int*)(agg + (size_t)N_NODES * HID);   // 50000
    int*   cursor = cnt + N_NODES;                    // 50000 (also scan scratch)
    int*   eidx   = cursor + N_NODES;                 // 800000
    int*   tsum   = eidx + E_EDGES;                   // 256
    int*   toff   = tsum + 256;                       // 256

    // cnt must be zero before prep's fused hist
    hipMemsetAsync(cnt, 0, N_NODES * sizeof(int), stream);

    // fused prep: h cvt + agg zero + hist + weight cvts (one launch)
    prep_kernel<<<PREP_WN2, 256, 0, stream>>>(h, hbf, agg, row, cnt,
                                              We1, be1, Wab, wrf,
                                              We2, be2, Wb2,
                                              Wn1, bn1, Wbn1, Wn2, bn2, Wbn2);

    // node-level layer-1 precompute (one half per block; grid 2x tiles)
    hab_kernel<<<((N_NODES + NB - 1) / NB) * 2, 256, 0, stream>>>(hbf, Wab, hab);

    // parallel CSR scan -> cursor
    scanA_kernel<<<NTILES, 256, 0, stream>>>(cnt, cursor, tsum);
    scanB_kernel<<<1, 256, 0, stream>>>(tsum, toff);
    scanC_kernel<<<NTILES, 256, 0, stream>>>(cnt, cursor, toff);
    fill_kernel<<<(E_EDGES + 255) / 256, 256, 0, stream>>>(row, cursor, eidx);

    // main
    edge_kernel<<<E_EDGES / ME, 256, 0, stream>>>(hab, cd, row, col, eidx, wrf,
                                                  Wb2, agg);
    node_kernel<<<(N_NODES + NB - 1) / NB, 256, 0, stream>>>(hbf, agg, Wbn1, Wbn2, out);
}

// Round 10
// 469.645 us; speedup vs baseline: 1.0200x; 1.0200x over previous
//
#include <hip/hip_runtime.h>
#include <cstdint>
#include <cstddef>

#define E_EDGES 800000
#define N_NODES 50000
#define HDIM 128
#define HID 256
#define ME 64            // edges per block in edge kernel
#define NB 64            // nodes per block in node/hab kernels
#define NTILES 196       // ceil(N_NODES/256) for the parallel scan

typedef __attribute__((ext_vector_type(8))) short short8;
typedef __attribute__((ext_vector_type(4))) float f32x4;

// fast silu: y * rcp(1 + exp(-y)); v_rcp_f32 ~1ulp, fine vs bf16 rounding
__device__ __forceinline__ float silu(float y) {
    return y * __builtin_amdgcn_rcpf(1.0f + __expf(-y));
}

// native RNE f32 -> bf16
__device__ __forceinline__ short f2bfn(float f) {
    __bf16 b = (__bf16)f;
    return __builtin_bit_cast(short, b);
}
__device__ __forceinline__ float bf2f(short s) {
    return __uint_as_float(((unsigned int)(unsigned short)s) << 16);
}

// ---------------- fused prep: h cvt + agg zero + hist + all weight cvts ----------------
// (cnt must be zeroed BEFORE this kernel: hist atomicAdds into it here)
// Wab  [512][160]: c<256: k<128 = We1[c][k],        k=128 = be1[c], else 0   (A-half)
//                  c>=256: k<128 = We1[c-256][128+k], else 0                 (B-half)
// wrf  [256] f32 : We1[c][256]  (radial column, exact f32)
// Wb2  [256][288]: k<256 = We2, k=256 = be2, else 0
// Wbn1 [256][416]: k<384 = Wn1, k=384 = bn1, else 0
// Wbn2 [128][288]: k<256 = Wn2, k=256 = bn2, else 0
#define PREP_H    6250                    // h fp32->bf16, 1600000 short4
#define PREP_AGG  (PREP_H + 12500)        // agg zero, 3200000 float4
#define PREP_HIST (PREP_AGG + 3125)       // hist over 800000 edges
#define PREP_WAB  (PREP_HIST + 320)       // 512*160
#define PREP_WRF  (PREP_WAB + 1)          // 256 f32
#define PREP_WE2  (PREP_WRF + 288)
#define PREP_WN1  (PREP_WE2 + 416)
#define PREP_WN2  (PREP_WN1 + 144)
__global__ void prep_kernel(const float* __restrict__ h, short* __restrict__ hbf,
                            float* __restrict__ agg,
                            const int* __restrict__ row, int* __restrict__ cnt,
                            const float* __restrict__ We1, const float* __restrict__ be1,
                            short* __restrict__ Wab, float* __restrict__ wrf,
                            const float* __restrict__ We2, const float* __restrict__ be2,
                            short* __restrict__ Wb2,
                            const float* __restrict__ Wn1, const float* __restrict__ bn1,
                            short* __restrict__ Wbn1,
                            const float* __restrict__ Wn2, const float* __restrict__ bn2,
                            short* __restrict__ Wbn2) {
    const int b = blockIdx.x, t = threadIdx.x;
    if (b < PREP_H) {
        int i = b * 256 + t;                      // quad index
        float4 v = ((const float4*)h)[i];
        short4 s;
        s.x = f2bfn(v.x); s.y = f2bfn(v.y); s.z = f2bfn(v.z); s.w = f2bfn(v.w);
        ((short4*)hbf)[i] = s;
    } else if (b < PREP_AGG) {
        int i = (b - PREP_H) * 256 + t;           // float4 index
        ((float4*)agg)[i] = make_float4(0.f, 0.f, 0.f, 0.f);
    } else if (b < PREP_HIST) {
        int e = (b - PREP_AGG) * 256 + t;
        if (e < E_EDGES) atomicAdd(&cnt[row[e]], 1);
    } else if (b < PREP_WAB) {
        int idx = (b - PREP_HIST) * 256 + t;      // 512*160
        int c = idx / 160, k = idx - c * 160;
        short v = 0;
        if (c < 256) {
            if (k < 128)       v = f2bfn(We1[c * 257 + k]);
            else if (k == 128) v = f2bfn(be1[c]);
        } else {
            if (k < 128)       v = f2bfn(We1[(c - 256) * 257 + 128 + k]);
        }
        Wab[idx] = v;
    } else if (b < PREP_WRF) {
        wrf[t] = We1[t * 257 + 256];
    } else if (b < PREP_WE2) {
        int idx = (b - PREP_WRF) * 256 + t;       // 256*288
        int c = idx / 288, k = idx - c * 288;
        short v = 0;
        if (k < 256)       v = f2bfn(We2[c * 256 + k]);
        else if (k == 256) v = f2bfn(be2[c]);
        Wb2[idx] = v;
    } else if (b < PREP_WN1) {
        int idx = (b - PREP_WE2) * 256 + t;       // 256*416
        int c = idx / 416, k = idx - c * 416;
        short v = 0;
        if (k < 384)       v = f2bfn(Wn1[c * 384 + k]);
        else if (k == 384) v = f2bfn(bn1[c]);
        Wbn1[idx] = v;
    } else {
        int idx = (b - PREP_WN1) * 256 + t;       // 128*288
        int c = idx / 288, k = idx - c * 288;
        short v = 0;
        if (k < 256)       v = f2bfn(Wn2[c * 256 + k]);
        else if (k == 256) v = f2bfn(bn2[c]);
        Wbn2[idx] = v;
    }
}

// ---------------- parallel CSR scan (3 small kernels) ----------------
__global__ void scanA_kernel(const int* __restrict__ cnt, int* __restrict__ incl,
                             int* __restrict__ tsum) {
    const int b = blockIdx.x, t = threadIdx.x;
    const int i = b * 256 + t;
    const int lane = t & 63, wv = t >> 6;
    int v = (i < N_NODES) ? cnt[i] : 0;
    int s = v;
#pragma unroll
    for (int off = 1; off < 64; off <<= 1) {
        int u = __shfl_up(s, off, 64);
        if (lane >= off) s += u;
    }
    __shared__ int wsum[4];
    if (lane == 63) wsum[wv] = s;
    __syncthreads();
    int pre = 0;
#pragma unroll
    for (int j = 0; j < 3; ++j) if (wv > j) pre += wsum[j];
    s += pre;
    if (i < N_NODES) incl[i] = s;
    if (t == 255) tsum[b] = s;
}

__global__ void scanB_kernel(const int* __restrict__ tsum, int* __restrict__ toff) {
    const int t = threadIdx.x;
    const int lane = t & 63, wv = t >> 6;
    int v = (t < NTILES) ? tsum[t] : 0;
    int s = v;
#pragma unroll
    for (int off = 1; off < 64; off <<= 1) {
        int u = __shfl_up(s, off, 64);
        if (lane >= off) s += u;
    }
    __shared__ int wsum[4];
    if (lane == 63) wsum[wv] = s;
    __syncthreads();
    int pre = 0;
#pragma unroll
    for (int j = 0; j < 3; ++j) if (wv > j) pre += wsum[j];
    s += pre;
    if (t < NTILES) toff[t] = s - v;   // exclusive
}

__global__ void scanC_kernel(const int* __restrict__ cnt, int* __restrict__ cursor,
                             const int* __restrict__ toff) {
    const int b = blockIdx.x, t = threadIdx.x;
    const int i = b * 256 + t;
    if (i < N_NODES) {
        cursor[i] = cursor[i] - cnt[i] + toff[b];   // incl -> excl + tile offset
    }
}

__global__ void fill_kernel(const int* __restrict__ row, int* __restrict__ cursor,
                            int* __restrict__ eidx) {
    int e = blockIdx.x * 256 + threadIdx.x;
    if (e < E_EDGES) {
        int pos = atomicAdd(&cursor[row[e]], 1);
        eidx[pos] = e;
    }
}

// ---------------- hab precompute: hab[n] = [h.Wa^T + be1 | h.Wb^T] (bf16) ----------------
// r24-proven: swapped-MFMA epilogue (lane holds 4 consecutive channels) ->
// packed short4 LDS stores -> coalesced short8 copy-out (8 chunks/thread).
__global__ __launch_bounds__(256, 4) void hab_kernel(
    const short* __restrict__ hbf, const short* __restrict__ Wab,
    short* __restrict__ hab)
{
    __shared__ __align__(16) short pool[NB * 256];  // 32 KB: shH (16KB) in GEMM; shO overlays
    __shared__ __align__(16) short shTh[NB * 32];   // 4 KB bias K-tail {1,0,..}
    short* shH = pool;                  // [64][128] bf16 (swizzled) during GEMM
    short* shO = pool;                  // [64][256] bf16 (swizzled) after barrier

    const int t = threadIdx.x;
    const int tile = blockIdx.x >> 1;
    const int half = blockIdx.x & 1;
    const int n0 = tile * NB;

    {
        const int n = t >> 2, q = t & 3;
        int gn = n0 + n;
        if (gn >= N_NODES) gn = N_NODES - 1;   // clamp loads; stores guarded
        const short8* hp = (const short8*)(hbf + (size_t)gn * HDIM + q * 32);
#pragma unroll
        for (int c = 0; c < 4; ++c) {
            short8 v = hp[c];
            int chunk = q * 4 + c;             // 0..15
            *(short8*)&shH[n * 128 + ((chunk ^ (n & 7)) << 3)] = v;
        }
        short8 z = {0, 0, 0, 0, 0, 0, 0, 0};
        if (q == 0) z[0] = (short)0x3F80;      // bf16 1.0
        *(short8*)&shTh[n * 32 + ((q ^ (n & 3)) << 3)] = z;
    }
    __syncthreads();

    const int l = t & 63, w = t >> 6;
    const int l15 = l & 15, lq = l >> 4;

    f32x4 acc[4][4];                    // SWAPPED: acc[ct][et], rows=channels
#pragma unroll
    for (int i = 0; i < 4; ++i)
#pragma unroll
        for (int j = 0; j < 4; ++j) acc[i][j] = (f32x4){0.f, 0.f, 0.f, 0.f};

#pragma unroll
    for (int ks = 0; ks < 5; ++ks) {
        short8 a[4], b[4];
#pragma unroll
        for (int et = 0; et < 4; ++et) {
            int r = et * 16 + l15;
            if (ks < 4) {
                int chunk = ks * 4 + lq;
                a[et] = *(const short8*)&shH[r * 128 + ((chunk ^ (r & 7)) << 3)];
            } else {
                a[et] = *(const short8*)&shTh[r * 32 + ((lq ^ (r & 3)) << 3)];
            }
        }
#pragma unroll
        for (int ct = 0; ct < 4; ++ct) {
            int cc = half * 256 + w * 64 + ct * 16 + l15;
            b[ct] = *(const short8*)&Wab[cc * 160 + ks * 32 + lq * 8];
        }
#pragma unroll
        for (int et = 0; et < 4; ++et)
#pragma unroll
            for (int ct = 0; ct < 4; ++ct)
                acc[ct][et] = __builtin_amdgcn_mfma_f32_16x16x32_bf16(
                    b[ct], a[et], acc[ct][et], 0, 0, 0);
    }
    __syncthreads();   // done reading shH before shO overlay

    // ---- swapped epilogue: packed short4 LDS stores (bank floor) ----
    {
#pragma unroll
        for (int ct = 0; ct < 4; ++ct) {
#pragma unroll
            for (int et = 0; et < 4; ++et) {
                int n = et * 16 + l15;                 // node (acc col)
                int chb = w * 64 + ct * 16 + lq * 4;   // within-half channel base
                short4 s;
                s.x = f2bfn(acc[ct][et][0]);
                s.y = f2bfn(acc[ct][et][1]);
                s.z = f2bfn(acc[ct][et][2]);
                s.w = f2bfn(acc[ct][et][3]);
                int chunk = chb >> 3;                  // chb % 4 == 0: stays in one chunk
                *(short4*)&shO[n * 256 + ((chunk ^ (n & 7)) << 3) + (chb & 7)] = s;
            }
        }
    }
    __syncthreads();

    // ---- coalesced copy-out: 4 threads/node, 8x short8 (16B) each = 256 ch ----
    {
        const int n = t >> 2, q = t & 3;
        int gn = n0 + n;
        if (gn < N_NODES) {
            short* dst = hab + (size_t)gn * 512 + half * 256;
#pragma unroll
            for (int c = 0; c < 8; ++c) {
                int chunk = c * 4 + q;                 // 0..31
                short8 v = *(const short8*)&shO[n * 256 + ((chunk ^ (n & 7)) << 3)];
                *(short8*)&dst[chunk * 8] = v;
            }
        }
    }
}

// ---------------- edge MLP (layer-1 fused into staging) + segmented scatter ----------------
// r26: staging/MFMA = r24 best (354us). Reduction rewritten: eidx is CSR-sorted,
// so a segment that starts AND ends strictly inside the block's 64-edge window
// is exclusively owned -> plain coalesced store (full sum over zeros). Only the
// first and last segments can be shared across blocks -> atomicAdd. Cuts
// device-scope f32 atomics 16M -> ~6.4M. Theory: memory-side atomic RMW
// serialization (16 lanes/line) is the invisible ~46%-stall resource that
// pinned r17-r25 at ~355us regardless of staging scheme.
__global__ __launch_bounds__(256, 4) void edge_kernel(
    const short* __restrict__ hab, const float* __restrict__ coord,
    const int* __restrict__ row, const int* __restrict__ col,
    const int* __restrict__ eidx, const float* __restrict__ wrf,
    const short* __restrict__ Wb2, float* __restrict__ agg)
{
    __shared__ __align__(16) short shPool[ME * 256 + ME * 32];
    __shared__ int sr[ME];
    short* shA = shPool;
    short* shT = shPool + ME * 256;

    const int t = threadIdx.x;
    const int nwg = E_EDGES / ME;
    const int qq = nwg >> 3, rr = nwg & 7;
    const int xcd = blockIdx.x & 7, bi = blockIdx.x >> 3;
    const int wg = (xcd < rr ? xcd * (qq + 1) : rr * (qq + 1) + (xcd - rr) * qq) + bi;
    const int e0 = wg * ME;

    // ---- stage: batched gather of A/B rows, fuse radial + silu -> M1 (swizzled) ----
    {
        const int e = t >> 2, q = t & 3;       // 4 threads/edge, 64 ch each
        const int eo = eidx[e0 + e];
        const int rsrc = row[eo];
        const int csrc = col[eo];
        const short8* Ap = (const short8*)(hab + (size_t)rsrc * 512 + q * 64);
        const short8* Bp = (const short8*)(hab + (size_t)csrc * 512 + 256 + q * 64);
        short8 av[8], bv[8];
#pragma unroll
        for (int j = 0; j < 8; ++j) av[j] = Ap[j];
#pragma unroll
        for (int j = 0; j < 8; ++j) bv[j] = Bp[j];
        float cx = coord[3 * eo + 0];
        float cy = coord[3 * eo + 1];
        float cz = coord[3 * eo + 2];
        float radial = cx * cx + cy * cy + cz * cz;
        const f32x4* Wp = (const f32x4*)(wrf + q * 64);
#pragma unroll
        for (int j = 0; j < 8; ++j) {
            f32x4 w0 = Wp[2 * j], w1 = Wp[2 * j + 1];
            short8 o;
#pragma unroll
            for (int u = 0; u < 4; ++u) {
                float y = bf2f(av[j][u]) + bf2f(bv[j][u]) + radial * w0[u];
                o[u] = f2bfn(silu(y));
            }
#pragma unroll
            for (int u = 0; u < 4; ++u) {
                float y = bf2f(av[j][4 + u]) + bf2f(bv[j][4 + u]) + radial * w1[u];
                o[4 + u] = f2bfn(silu(y));
            }
            int chunk = q * 8 + j;
            *(short8*)&shA[e * 256 + ((chunk ^ (e & 7)) << 3)] = o;
        }
        short8 z = {0, 0, 0, 0, 0, 0, 0, 0};
        if (q == 0) {
            z[0] = (short)0x3F80;              // bf16 1.0 (bias multiplier)
            sr[e] = rsrc;
        }
        *(short8*)&shT[e * 32 + ((q ^ (e & 3)) << 3)] = z;
    }
    __syncthreads();

    const int l = t & 63, w = t >> 6;
    const int l15 = l & 15, lq = l >> 4;

    // ---- layer 2: K=256 (+32 tail: bias) MFMA ----
    f32x4 acc[4][4];
#pragma unroll
    for (int i = 0; i < 4; ++i)
#pragma unroll
        for (int j = 0; j < 4; ++j) acc[i][j] = (f32x4){0.f, 0.f, 0.f, 0.f};
#pragma unroll
    for (int ks = 0; ks < 8; ++ks) {
        short8 a[4], b[4];
#pragma unroll
        for (int et = 0; et < 4; ++et) {
            int r = et * 16 + l15;
            int chunk = ks * 4 + lq;
            a[et] = *(const short8*)&shA[r * 256 + ((chunk ^ (r & 7)) << 3)];
        }
#pragma unroll
        for (int ct = 0; ct < 4; ++ct) {
            int cc = w * 64 + ct * 16 + l15;
            b[ct] = *(const short8*)&Wb2[cc * 288 + ks * 32 + lq * 8];
        }
        __builtin_amdgcn_s_setprio(1);
#pragma unroll
        for (int et = 0; et < 4; ++et)
#pragma unroll
            for (int ct = 0; ct < 4; ++ct)
                acc[et][ct] = __builtin_amdgcn_mfma_f32_16x16x32_bf16(
                    a[et], b[ct], acc[et][ct], 0, 0, 0);
        __builtin_amdgcn_s_setprio(0);
    }
    {   // tail K-step: bias (A = {1.0,0...})
        short8 a[4], b[4];
#pragma unroll
        for (int et = 0; et < 4; ++et) {
            int r = et * 16 + l15;
            a[et] = *(const short8*)&shT[r * 32 + ((lq ^ (r & 3)) << 3)];
        }
#pragma unroll
        for (int ct = 0; ct < 4; ++ct) {
            int cc = w * 64 + ct * 16 + l15;
            b[ct] = *(const short8*)&Wb2[cc * 288 + 256 + lq * 8];
        }
        __builtin_amdgcn_s_setprio(1);
#pragma unroll
        for (int et = 0; et < 4; ++et)
#pragma unroll
            for (int ct = 0; ct < 4; ++ct)
                acc[et][ct] = __builtin_amdgcn_mfma_f32_16x16x32_bf16(
                    a[et], b[ct], acc[et][ct], 0, 0, 0);
        __builtin_amdgcn_s_setprio(0);
    }
    __syncthreads();

    // ---- SiLU -> C2 TRANSPOSED [n][e], stride 68, packed short4 writes ----
    {
#pragma unroll
        for (int ct = 0; ct < 4; ++ct) {
#pragma unroll
            for (int et = 0; et < 4; ++et) {
                int kc = w * 64 + ct * 16 + l15;
                int er0 = et * 16 + lq * 4;
                short4 s;
                s.x = f2bfn(silu(acc[et][ct][0]));
                s.y = f2bfn(silu(acc[et][ct][1]));
                s.z = f2bfn(silu(acc[et][ct][2]));
                s.w = f2bfn(silu(acc[et][ct][3]));
                *(short4*)&shPool[kc * 68 + er0] = s;
            }
        }
    }
    __syncthreads();

    // ---- segmented reduction: interior segments -> plain store (block-exclusive
    //      since eidx is CSR-contiguous); first/last segments -> atomicAdd ----
    {
        const int cc = t;
        const short* myrow = &shPool[cc * 68];
        float accum = 0.f;
        int cur = __builtin_amdgcn_readfirstlane(sr[0]);
        bool headSeg = true;                 // current segment touches block start
        for (int eb = 0; eb < ME; eb += 4) {
            short4 v4 = *(const short4*)&myrow[eb];
            short vj[4] = {v4.x, v4.y, v4.z, v4.w};
#pragma unroll
            for (int j = 0; j < 4; ++j) {
                float v = bf2f(vj[j]);
                int r = __builtin_amdgcn_readfirstlane(sr[eb + j]);
                if (r != cur) {
                    if (headSeg) {
                        atomicAdd(&agg[(size_t)cur * HID + cc], accum);
                        headSeg = false;
                    } else {
                        agg[(size_t)cur * HID + cc] = accum;   // exclusive: overwrite zero
                    }
                    accum = v;
                    cur = r;
                } else {
                    accum += v;
                }
            }
        }
        atomicAdd(&agg[(size_t)cur * HID + cc], accum);   // tail segment: may be shared
    }
}

// ---------------- node MLP (bf16 MFMA), 64 nodes/block, biases via MFMA tails ----------------
__global__ __launch_bounds__(256, 3) void node_kernel(
    const short* __restrict__ hbf, const float* __restrict__ agg,
    const short* __restrict__ Wbn1, const short* __restrict__ Wbn2,
    float* __restrict__ out)
{
    __shared__ __align__(16) short pool[NB * 384];  // 48 KB: shH + shAg; shM overlays
    __shared__ __align__(16) short shTn[NB * 32];   // 4 KB bias K-tail {1,0,..}
    short* shH  = pool;                 // [64][128] bf16 (swizzled)
    short* shAg = pool + NB * 128;      // [64][256] bf16 (swizzled)
    short* shM  = pool;                 // [64][256] bf16 (swizzled) — overlays

    const int t  = threadIdx.x;
    const int n0 = blockIdx.x * NB;

    // ---- stage h (bf16 copy), agg (f32 -> bf16), bias tail; 4 threads/node ----
    {
        const int n = t >> 2, q = t & 3;
        int gn = n0 + n;
        if (gn >= N_NODES) gn = N_NODES - 1;   // clamp loads; stores guarded later
        const short8* hp = (const short8*)(hbf + (size_t)gn * HDIM + q * 32);
#pragma unroll
        for (int c = 0; c < 4; ++c) {
            short8 v = hp[c];
            int chunk = q * 4 + c;             // 0..15
            int sw = chunk ^ (n & 7);
            *(short8*)&shH[n * 128 + sw * 8] = v;
        }
        const float4* ap = (const float4*)(agg + (size_t)gn * HID + q * 64);
#pragma unroll
        for (int i = 0; i < 8; ++i) {
            float4 u0 = ap[2 * i], u1 = ap[2 * i + 1];
            short8 s;
            s[0] = f2bfn(u0.x); s[1] = f2bfn(u0.y); s[2] = f2bfn(u0.z); s[3] = f2bfn(u0.w);
            s[4] = f2bfn(u1.x); s[5] = f2bfn(u1.y); s[6] = f2bfn(u1.z); s[7] = f2bfn(u1.w);
            int chunk = q * 8 + i;             // 0..31
            int sw2 = chunk ^ (n & 7);
            *(short8*)&shAg[n * 256 + sw2 * 8] = s;
        }
        short8 z = {0, 0, 0, 0, 0, 0, 0, 0};
        if (q == 0) z[0] = (short)0x3F80;      // bf16 1.0
        *(short8*)&shTn[n * 32 + ((q ^ (n & 3)) << 3)] = z;
    }
    __syncthreads();

    const int l = t & 63, w = t >> 6;
    const int l15 = l & 15, lq = l >> 4;

    // ---- layer 1: K=384 (+32 bias tail), 256 cols, 64 rows ----
    f32x4 acc[4][4];
#pragma unroll
    for (int i = 0; i < 4; ++i)
#pragma unroll
        for (int j = 0; j < 4; ++j) acc[i][j] = (f32x4){0.f, 0.f, 0.f, 0.f};
#pragma unroll
    for (int ks = 0; ks < 12; ++ks) {
        short8 a[4], b[4];
#pragma unroll
        for (int et = 0; et < 4; ++et) {
            int r = et * 16 + l15;
            if (ks < 4) {
                int chunk = ks * 4 + lq;
                a[et] = *(const short8*)&shH[r * 128 + ((chunk ^ (r & 7)) << 3)];
            } else {
                int chunk = (ks - 4) * 4 + lq;
                a[et] = *(const short8*)&shAg[r * 256 + ((chunk ^ (r & 7)) << 3)];
            }
        }
#pragma unroll
        for (int ct = 0; ct < 4; ++ct) {
            int cc = w * 64 + ct * 16 + l15;
            b[ct] = *(const short8*)&Wbn1[cc * 416 + ks * 32 + lq * 8];
        }
#pragma unroll
        for (int et = 0; et < 4; ++et)
#pragma unroll
            for (int ct = 0; ct < 4; ++ct)
                acc[et][ct] = __builtin_amdgcn_mfma_f32_16x16x32_bf16(
                    a[et], b[ct], acc[et][ct], 0, 0, 0);
    }
    {   // bias tail (k = 384..415)
        short8 a[4], b[4];
#pragma unroll
        for (int et = 0; et < 4; ++et) {
            int r = et * 16 + l15;
            a[et] = *(const short8*)&shTn[r * 32 + ((lq ^ (r & 3)) << 3)];
        }
#pragma unroll
        for (int ct = 0; ct < 4; ++ct) {
            int cc = w * 64 + ct * 16 + l15;
            b[ct] = *(const short8*)&Wbn1[cc * 416 + 384 + lq * 8];
        }
#pragma unroll
        for (int et = 0; et < 4; ++et)
#pragma unroll
            for (int ct = 0; ct < 4; ++ct)
                acc[et][ct] = __builtin_amdgcn_mfma_f32_16x16x32_bf16(
                    a[et], b[ct], acc[et][ct], 0, 0, 0);
    }
    __syncthreads();   // done reading shH/shAg before shM overlay write

    // ---- SiLU -> M (bf16, swizzled; no bias add) ----
    {
#pragma unroll
        for (int et = 0; et < 4; ++et) {
#pragma unroll
            for (int rp = 0; rp < 2; ++rp) {
                int er0 = et * 16 + lq * 4 + rp * 2;
#pragma unroll
                for (int ct = 0; ct < 4; ++ct) {
                    int kc = w * 64 + ct * 16 + l15;
                    float y0 = silu(acc[et][ct][rp * 2]);
                    float y1 = silu(acc[et][ct][rp * 2 + 1]);
                    int khi = kc >> 3, klo = kc & 7;
                    shM[er0 * 256 + ((khi ^ (er0 & 7)) << 3) + klo] = f2bfn(y0);
                    shM[(er0 + 1) * 256 + ((khi ^ ((er0 + 1) & 7)) << 3) + klo] = f2bfn(y1);
                }
            }
        }
    }
    __syncthreads();

    // ---- layer 2: K=256 (+32 bias tail), 128 cols (32 per wave), 64 rows ----
    f32x4 acc2[4][2];
#pragma unroll
    for (int i = 0; i < 4; ++i)
#pragma unroll
        for (int j = 0; j < 2; ++j) acc2[i][j] = (f32x4){0.f, 0.f, 0.f, 0.f};
#pragma unroll
    for (int ks = 0; ks < 8; ++ks) {
        short8 a[4], b2[2];
#pragma unroll
        for (int et = 0; et < 4; ++et) {
            int r = et * 16 + l15;
            int chunk = ks * 4 + lq;
            a[et] = *(const short8*)&shM[r * 256 + ((chunk ^ (r & 7)) << 3)];
        }
#pragma unroll
        for (int ct = 0; ct < 2; ++ct) {
            int cc = w * 32 + ct * 16 + l15;
            b2[ct] = *(const short8*)&Wbn2[cc * 288 + ks * 32 + lq * 8];
        }
#pragma unroll
        for (int et = 0; et < 4; ++et)
#pragma unroll
            for (int ct = 0; ct < 2; ++ct)
                acc2[et][ct] = __builtin_amdgcn_mfma_f32_16x16x32_bf16(
                    a[et], b2[ct], acc2[et][ct], 0, 0, 0);
    }
    {   // bias tail (k = 256..287); shTn not overlaid
        short8 a[4], b2[2];
#pragma unroll
        for (int et = 0; et < 4; ++et) {
            int r = et * 16 + l15;
            a[et] = *(const short8*)&shTn[r * 32 + ((lq ^ (r & 3)) << 3)];
        }
#pragma unroll
        for (int ct = 0; ct < 2; ++ct) {
            int cc = w * 32 + ct * 16 + l15;
            b2[ct] = *(const short8*)&Wbn2[cc * 288 + 256 + lq * 8];
        }
#pragma unroll
        for (int et = 0; et < 4; ++et)
#pragma unroll
            for (int ct = 0; ct < 2; ++ct)
                acc2[et][ct] = __builtin_amdgcn_mfma_f32_16x16x32_bf16(
                    a[et], b2[ct], acc2[et][ct], 0, 0, 0);
    }

    // ---- store (bias already in acc2) ----
#pragma unroll
    for (int et = 0; et < 4; ++et) {
#pragma unroll
        for (int ct = 0; ct < 2; ++ct) {
            int cc = w * 32 + ct * 16 + l15;
#pragma unroll
            for (int r4 = 0; r4 < 4; ++r4) {
                int gn = n0 + et * 16 + lq * 4 + r4;
                if (gn < N_NODES)
                    out[(size_t)gn * HDIM + cc] = acc2[et][ct][r4];
            }
        }
    }
}

extern "C" void kernel_launch(void* const* d_in, const int* in_sizes, int n_in,
                              void* d_out, int out_size, void* d_ws, size_t ws_size,
                              hipStream_t stream) {
    const float* h   = (const float*)d_in[0];
    const float* cd  = (const float*)d_in[1];
    const int*   row = (const int*)d_in[2];
    const int*   col = (const int*)d_in[3];
    const float* We1 = (const float*)d_in[4];
    const float* be1 = (const float*)d_in[5];
    const float* We2 = (const float*)d_in[6];
    const float* be2 = (const float*)d_in[7];
    const float* Wn1 = (const float*)d_in[8];
    const float* bn1 = (const float*)d_in[9];
    const float* Wn2 = (const float*)d_in[10];
    const float* bn2 = (const float*)d_in[11];
    float* out = (float*)d_out;

    // ---- workspace layout ----
    short* Wab  = (short*)d_ws;                       // 512*160
    short* Wb2  = Wab + 512 * 160;                    // 256*288
    short* Wbn1 = Wb2 + 256 * 288;                    // 256*416
    short* Wbn2 = Wbn1 + 256 * 416;                   // 128*288
    float* wrf  = (float*)(Wbn2 + 128 * 288);         // 256 f32
    short* hbf  = (short*)(wrf + 256);                // 50000*128
    short* hab  = hbf + (size_t)N_NODES * HDIM;       // 50000*512 bf16
    float* agg  = (float*)(hab + (size_t)N_NODES * 512);   // 50000*256 f32
    int*   cnt    = (int*)(agg + (size_t)N_NODES * HID);   // 50000
    int*   cursor = cnt + N_NODES;                    // 50000 (also scan scratch)
    int*   eidx   = cursor + N_NODES;                 // 800000
    int*   tsum   = eidx + E_EDGES;                   // 256
    int*   toff   = tsum + 256;                       // 256

    // cnt must be zero before prep's fused hist
    hipMemsetAsync(cnt, 0, N_NODES * sizeof(int), stream);

    // fused prep: h cvt + agg zero + hist + weight cvts (one launch)
    prep_kernel<<<PREP_WN2, 256, 0, stream>>>(h, hbf, agg, row, cnt,
                                              We1, be1, Wab, wrf,
                                              We2, be2, Wb2,
                                              Wn1, bn1, Wbn1, Wn2, bn2, Wbn2);

    // node-level layer-1 precompute (one half per block; grid 2x tiles)
    hab_kernel<<<((N_NODES + NB - 1) / NB) * 2, 256, 0, stream>>>(hbf, Wab, hab);

    // parallel CSR scan -> cursor
    scanA_kernel<<<NTILES, 256, 0, stream>>>(cnt, cursor, tsum);
    scanB_kernel<<<1, 256, 0, stream>>>(tsum, toff);
    scanC_kernel<<<NTILES, 256, 0, stream>>>(cnt, cursor, toff);
    fill_kernel<<<(E_EDGES + 255) / 256, 256, 0, stream>>>(row, cursor, eidx);

    // main
    edge_kernel<<<E_EDGES / ME, 256, 0, stream>>>(hab, cd, row, col, eidx, wrf,
                                                  Wb2, agg);
    node_kernel<<<(N_NODES + NB - 1) / NB, 256, 0, stream>>>(hbf, agg, Wbn1, Wbn2, out);
}